// Round 2
// baseline (674.842 us; speedup 1.0000x reference)
//
#include <hip/hip_runtime.h>
#include <cstdint>
#include <cstddef>

// Problem: B=32, C=768, H=W=32 (HW=1024).
// out[b,c,hw] = (0.5 + 0.5 * cos_gate(b,c)) * X[b,c,hw]
// cos_gate = dot(K_c,V_c)/((||K_c||+1e-12)(||V_c||+1e-12)),
// K = Wk @ Xn, V = Wv @ Xn, Xn = X * rsqrt(mean_c X^2 + 1e-6).
//
// This round: kill the 6x B(Xnt) re-stage amplification (r1 was bound at
// ~3 TB/s of L3-side supply). Each block owns a 64-wide hw slice with B held
// IN REGISTERS (24 x bf16x8 per lane, full K=768); A streams through LDS from
// the per-XCD-L2-resident 2.25 MB Wst. 256 persistent blocks x 2 items; item-2
// B is trickle-prefetched into LDS during item-1.

#define B_   32
#define C_   768
#define HW_  1024
#define CHW_ (C_ * HW_)          // 786432
#define EPS_NORM 1e-6f
#define EPS_COS  1e-12f

using f32x4  = __attribute__((ext_vector_type(4))) float;
using bf16x8 = __attribute__((ext_vector_type(8))) short;   // 8 bf16 = 4 VGPRs

__device__ inline unsigned short f2bf(float f) {
    union { float f; unsigned u; } v; v.f = f;
    unsigned u = v.u;
    u += 0x7fffu + ((u >> 16) & 1u);        // round-to-nearest-even
    return (unsigned short)(u >> 16);
}

// async global->LDS, 16 B per lane. LDS dst is wave-uniform base + lane*16;
// global src may be per-lane (pre-swizzled source pattern).
__device__ __forceinline__ void load16_lds(const unsigned short* g, short* l) {
    __builtin_amdgcn_global_load_lds(
        (const __attribute__((address_space(1))) unsigned int*)g,
        (__attribute__((address_space(3))) unsigned int*)l,
        16, 0, 0);
}

#define WAITVM(n) asm volatile("s_waitcnt vmcnt(" #n ")" ::: "memory")
#define SB0 __builtin_amdgcn_sched_barrier(0)

// ---------------------------------------------------------------------------
// K1: cast + row-interleave first 1536 rows of W_in (fp32) -> bf16.
// Wst[2c+s] = W[s*768 + c]. grid 1536 blocks x 192 threads (1 float4/thread).
// ---------------------------------------------------------------------------
__global__ void wconv_kernel(const float* __restrict__ W, unsigned short* __restrict__ Wst) {
    const int orow = blockIdx.x;               // 0..1535
    const int c4   = threadIdx.x;              // 0..191
    const int irow = (orow & 1) * 768 + (orow >> 1);
    const float4 v = reinterpret_cast<const float4*>(W + (size_t)irow * 768)[c4];
    ushort4 o;
    o.x = f2bf(v.x); o.y = f2bf(v.y); o.z = f2bf(v.z); o.w = f2bf(v.w);
    reinterpret_cast<ushort4*>(Wst + (size_t)orow * 768)[c4] = o;
}

// ---------------------------------------------------------------------------
// K2: channel sum-of-squares, float4 loads. (unchanged)
// ---------------------------------------------------------------------------
__global__ void sumsq_kernel(const float* __restrict__ X, float* __restrict__ ssum) {
    const int b  = blockIdx.y;
    const int c0 = blockIdx.x * 32;
    const int t  = threadIdx.x;                       // hw quad 0..255
    const float4* xp = reinterpret_cast<const float4*>(X + (size_t)b * CHW_ + (size_t)c0 * HW_) + t;
    float4 s = {0.f, 0.f, 0.f, 0.f};
    #pragma unroll 8
    for (int c = 0; c < 32; ++c) {
        float4 v = xp[c * 256];
        s.x += v.x * v.x; s.y += v.y * v.y; s.z += v.z * v.z; s.w += v.w * v.w;
    }
    float* dst = ssum + b * HW_ + t * 4;
    atomicAdd(dst + 0, s.x);
    atomicAdd(dst + 1, s.y);
    atomicAdd(dst + 2, s.z);
    atomicAdd(dst + 3, s.w);
}

// ---------------------------------------------------------------------------
// K3: Xn_t[b][hw][c] = bf16( X[b][c][hw] * rsqrt(ssum/768 + eps) )  (unchanged)
// ---------------------------------------------------------------------------
__global__ __launch_bounds__(256) void xnt_kernel(const float* __restrict__ X,
                                                  const float* __restrict__ ssum,
                                                  unsigned short* __restrict__ Xnt) {
    const int b   = blockIdx.z;
    const int c0  = blockIdx.y * 64;
    const int hw0 = blockIdx.x * 64;
    const int tid = threadIdx.x;
    __shared__ short T[64][78];

    #pragma unroll
    for (int it = 0; it < 4; ++it) {
        int q  = it * 256 + tid;        // 0..1023
        int r  = q >> 4;                // c row in tile
        int c4 = (q & 15) * 4;          // hw col in tile
        const float4 x = *reinterpret_cast<const float4*>(
            X + (size_t)b * CHW_ + (size_t)(c0 + r) * HW_ + hw0 + c4);
        const float4 s = *reinterpret_cast<const float4*>(ssum + b * HW_ + hw0 + c4);
        ushort4 o;
        o.x = f2bf(x.x * rsqrtf(s.x * (1.f / 768.f) + EPS_NORM));
        o.y = f2bf(x.y * rsqrtf(s.y * (1.f / 768.f) + EPS_NORM));
        o.z = f2bf(x.z * rsqrtf(s.z * (1.f / 768.f) + EPS_NORM));
        o.w = f2bf(x.w * rsqrtf(s.w * (1.f / 768.f) + EPS_NORM));
        *reinterpret_cast<ushort4*>(&T[r][c4]) = o;
    }
    __syncthreads();
    #pragma unroll
    for (int it = 0; it < 2; ++it) {
        int q  = it * 256 + tid;        // 0..511
        int rp = q >> 3;                // hw row
        int cc = (q & 7) * 8;           // c chunk
        __align__(16) unsigned short tmp[8];
        #pragma unroll
        for (int j = 0; j < 8; ++j) tmp[j] = (unsigned short)T[cc + j][rp];
        *reinterpret_cast<uint4*>(
            Xnt + (size_t)b * CHW_ + (size_t)(hw0 + rp) * C_ + c0 + cc) =
            *reinterpret_cast<const uint4*>(tmp);
    }
}

// ---------------------------------------------------------------------------
// K4: persistent 1536x64 GEMM + fused reductions.
// 256 blocks x 512 thr (8 waves = 2 M-groups x 4 N-waves of 16 hw cols).
// B: 24 x bf16x8 regs/lane (full K=768 of this wave's 16 hw cols).
// A: LDS dbuf sA[2][192][64] (m-subtile 192 rows, BK=64), staged-for-next with
//    top-of-phase counted vmcnt; ONE barrier per phase (stage of phase p is
//    issued after p's top barrier, by which time all p-1 reads completed).
// Swizzle: chunk^(row&7) pre-swizzled global source, XOR on ds_read (r1-proven).
// vmcnt bookkeeping (static): 3 A-stage loads/phase; +1 in pref-shadow phases
// (vmcnt(1) at k in 3..6 of pref m-steps); +36 epilogue atomics (vmcnt(36) at
// k==0, m>0). Item boundary: vmcnt(0)+barrier, reload B regs from sBpre.
// ---------------------------------------------------------------------------
__device__ __forceinline__ void epilogue(f32x4 (&acc)[6], float* wsAb,
                                         int g48, int m, int quad) {
    const int chBase = m * 96 + g48 + quad * 2;
    const f32x4 vz = {0.f, 0.f, 0.f, 0.f};
    #pragma unroll
    for (int mi = 0; mi < 6; ++mi) {
        f32x4 a = acc[mi];
        // C rows (4*quad + r): interleaved (K,V,K,V) of 2 channels.
        float d0 = a[0]*a[1], e0 = a[0]*a[0], f0 = a[1]*a[1];
        float d1 = a[2]*a[3], e1 = a[2]*a[2], f1 = a[3]*a[3];
        #pragma unroll
        for (int off = 1; off < 16; off <<= 1) {
            d0 += __shfl_xor(d0, off); e0 += __shfl_xor(e0, off); f0 += __shfl_xor(f0, off);
            d1 += __shfl_xor(d1, off); e1 += __shfl_xor(e1, off); f1 += __shfl_xor(f1, off);
        }
        if ((threadIdx.x & 15) == 0) {          // 36 atomic instrs per wave total
            float* dst = wsAb + (size_t)(chBase + mi * 8) * 3;
            atomicAdd(dst + 0, d0); atomicAdd(dst + 1, e0); atomicAdd(dst + 2, f0);
            atomicAdd(dst + 3, d1); atomicAdd(dst + 4, e1); atomicAdd(dst + 5, f1);
        }
        acc[mi] = vz;
    }
}

template<bool FIRST, bool PREF>
__device__ __forceinline__ void mstep(
    const short* Ar0, const short* Ar1, short* st0, short* st1,
    const unsigned short* gAk, const unsigned short* gAnext,
    const unsigned short* gBp, short* pB, int prefC,
    int slot0, int slot1, bf16x8 (&Breg)[24], f32x4 (&acc)[6])
{
#define PHASE(kk) do { \
    if ((kk) == 0)      { if (FIRST) { WAITVM(0); } else { WAITVM(36); } } \
    else if (PREF && (kk) >= 3 && (kk) <= 6) { WAITVM(1); } \
    else                { WAITVM(0); } \
    SB0; __builtin_amdgcn_s_barrier(); SB0; \
    { short* st_ = ((kk) & 1) ? st0 : st1;               /* buf (kk+1)&1 */ \
      const unsigned short* g_ = ((kk) < 11) ? (gAk + ((kk) + 1) * 64) : gAnext; \
      load16_lds(g_,         st_); \
      load16_lds(g_ + 49152, st_ + 4096); \
      load16_lds(g_ + 98304, st_ + 8192); } \
    if (PREF && (kk) >= 2 && (kk) <= 5) \
      load16_lds(gBp + (size_t)(prefC + (kk) - 2) * 64, pB + (prefC + (kk) - 2) * 4096); \
    SB0; \
    { const short* ar_ = ((kk) & 1) ? Ar1 : Ar0;         /* buf kk&1 */ \
      __builtin_amdgcn_s_setprio(1); \
      _Pragma("unroll") \
      for (int mi_ = 0; mi_ < 6; ++mi_) { \
        bf16x8 aa0 = *reinterpret_cast<const bf16x8*>(ar_ + (mi_ << 10) + slot0); \
        bf16x8 aa1 = *reinterpret_cast<const bf16x8*>(ar_ + (mi_ << 10) + slot1); \
        acc[mi_] = __builtin_amdgcn_mfma_f32_16x16x32_bf16(aa0, Breg[2*(kk)],   acc[mi_], 0, 0, 0); \
        acc[mi_] = __builtin_amdgcn_mfma_f32_16x16x32_bf16(aa1, Breg[2*(kk)+1], acc[mi_], 0, 0, 0); } \
      __builtin_amdgcn_s_setprio(0); } \
    SB0; \
} while (0)
    PHASE(0); PHASE(1); PHASE(2); PHASE(3); PHASE(4);  PHASE(5);
    PHASE(6); PHASE(7); PHASE(8); PHASE(9); PHASE(10); PHASE(11);
#undef PHASE
}

__global__ __launch_bounds__(512, 2) void gemm_kernel(
        const unsigned short* __restrict__ Wst,   // [1536][768] bf16, interleaved K/V
        const unsigned short* __restrict__ Xnt,   // [B][HW][C] bf16
        float* __restrict__ wsA) {
    const int bid  = blockIdx.x;                  // 0..255
    const int tid  = threadIdx.x;
    const int lane = tid & 63;
    const int wave = tid >> 6;
    const int l15  = lane & 15;
    const int quad = lane >> 4;
    const int lb7  = l15 & 7;
    const int g96  = (wave >> 2) * 96;            // M-group row base in 192-tile
    const int wn   = (wave & 3) << 4;             // hw-col base within 64

    __shared__ __align__(16) short sA[2][192][64];     // 48 KB
    __shared__ __align__(16) short sBpre[96 * 512];    // 96 KB (item-2 B)

    // A staging map (r1-proven): r0 = tid>>3 (64 rows/call), chunk pre-swizzled.
    const int r0      = tid >> 3;
    const size_t toff = (size_t)r0 * 768 + (((tid & 7) ^ (r0 & 7)) << 3);
    const int ldsA    = (r0 & ~7) << 6;           // wave-uniform (shorts)
    short* st0 = &sA[0][0][0] + ldsA;
    short* st1 = &sA[1][0][0] + ldsA;
    const short* Ar0 = &sA[0][0][0] + ((g96 + l15) << 6);
    const short* Ar1 = &sA[1][0][0] + ((g96 + l15) << 6);
    const int slot0 = (quad ^ lb7) << 3;          // k-step 0 swizzled slot (shorts)
    const int slot1 = ((quad + 4) ^ lb7) << 3;    // k-step 1

    const int it0 = bid, it1 = bid + 256;         // item ids: b = it>>4, hw0 = (it&15)*64

    f32x4 acc[6];
    const f32x4 vz = {0.f, 0.f, 0.f, 0.f};
    #pragma unroll
    for (int i = 0; i < 6; ++i) acc[i] = vz;

    // item-1 B into registers: lane (l15,quad) holds Xnt[b][hw0+wn+l15][32ks+8q..+7]
    bf16x8 Breg[24];
    {
        const unsigned short* gB = Xnt
            + ((size_t)(it0 >> 4) * HW_ + (size_t)((it0 & 15) << 6) + wn + l15) * 768 + quad * 8;
        #pragma unroll
        for (int ks = 0; ks < 24; ++ks)
            Breg[ks] = *reinterpret_cast<const bf16x8*>(gB + ks * 32);
    }
    // item-2 B prefetch: src per-lane, LDS dst wave-uniform + lane*16.
    // call c stages ksq-octets [8c,8c+8) for all 64 hw: flat tid*16B layout.
    const unsigned short* gBp = Xnt
        + ((size_t)(it1 >> 4) * HW_ + (size_t)((it1 & 15) << 6) + (tid & 63)) * 768
        + ((tid >> 6) << 3);
    short* pB = &sBpre[0] + ((tid >> 6) << 9);

    // prologue: stage (m=0, k=0) into buf0
    load16_lds(Wst + toff,         st0);
    load16_lds(Wst + toff + 49152, st0 + 4096);
    load16_lds(Wst + toff + 98304, st0 + 8192);

    #pragma unroll 1
    for (int item = 0; item < 2; ++item) {
        const int itc = (item == 0) ? it0 : it1;
        float* wsAb = wsA + (size_t)(itc >> 4) * (C_ * 3);

        mstep<true, false>(Ar0, Ar1, st0, st1, Wst + toff, Wst + 147456 + toff,
                           gBp, pB, 0, slot0, slot1, Breg, acc);
        epilogue(acc, wsAb, g96 >> 1, 0, quad);
        #pragma unroll 1
        for (int m = 1; m < 8; ++m) {
            const unsigned short* gAk = Wst + (size_t)m * 147456 + toff;
            const unsigned short* gAn = Wst + (size_t)((m + 1) & 7) * 147456 + toff;
            if (m >= 2 && m <= 4)
                mstep<false, true >(Ar0, Ar1, st0, st1, gAk, gAn, gBp, pB, (m - 2) * 4,
                                    slot0, slot1, Breg, acc);
            else
                mstep<false, false>(Ar0, Ar1, st0, st1, gAk, gAn, gBp, pB, 0,
                                    slot0, slot1, Breg, acc);
            epilogue(acc, wsAb, g96 >> 1, m, quad);
        }
        if (item == 0) {   // boundary: drain prefetch DMAs, reload B regs from LDS
            WAITVM(0); SB0;
            __builtin_amdgcn_s_barrier(); SB0;
            #pragma unroll
            for (int ks = 0; ks < 24; ++ks)
                Breg[ks] = *reinterpret_cast<const bf16x8*>(
                    &sBpre[(ks * 4 + quad) * 512 + ((wn + l15) << 3)]);
        }
    }
}

// ---------------------------------------------------------------------------
// K5: out = X * gate. (unchanged)
// ---------------------------------------------------------------------------
__global__ void final_kernel(const float* __restrict__ X, const float* __restrict__ wsA,
                             float* __restrict__ out) {
    const int bc = blockIdx.x;                 // b*768 + c
    const float* a = wsA + (size_t)bc * 3;
    const float pd = a[0], pk = a[1], pv = a[2];
    const float A = pd / ((sqrtf(pk) + EPS_COS) * (sqrtf(pv) + EPS_COS));
    const float g = 0.5f * A + 0.5f;
    const size_t i4 = (size_t)bc * 256 + threadIdx.x;
    float4 x = reinterpret_cast<const float4*>(X)[i4];
    float4 o;
    o.x = x.x * g; o.y = x.y * g; o.z = x.z * g; o.w = x.w * g;
    reinterpret_cast<float4*>(out)[i4] = o;
}

// ---------------------------------------------------------------------------
extern "C" void kernel_launch(void* const* d_in, const int* in_sizes, int n_in,
                              void* d_out, int out_size, void* d_ws, size_t ws_size,
                              hipStream_t stream) {
    const float* X = (const float*)d_in[0];   // [32,768,32,32]
    const float* W = (const float*)d_in[1];   // [2304,768]
    float* out = (float*)d_out;

    // workspace layout (bytes):
    //   [0,       294912)   wsA   float[32*768*3]  (dot, nk2, nv2)
    //   [294912,  425984)   ssum  float[32*1024]
    //   [425984,  2785280)  Wst   bf16[1536*768]   (interleaved K/V rows)
    //   [2785280, 53116928) Xnt   bf16[32][1024][768]
    char* ws = (char*)d_ws;
    float* wsA           = (float*)ws;
    float* ssum          = (float*)(ws + 294912);
    unsigned short* Wst  = (unsigned short*)(ws + 425984);
    unsigned short* Xnt  = (unsigned short*)(ws + 2785280);

    hipMemsetAsync(ws, 0, 425984, stream);    // zero wsA + ssum

    wconv_kernel<<<dim3(1536),       192, 0, stream>>>(W, Wst);
    sumsq_kernel<<<dim3(24, 32),     256, 0, stream>>>(X, ssum);
    xnt_kernel  <<<dim3(16, 12, 32), 256, 0, stream>>>(X, ssum, Xnt);
    gemm_kernel <<<dim3(256),        512, 0, stream>>>(Wst, Xnt, wsA);
    final_kernel<<<dim3(24576),      256, 0, stream>>>(X, wsA, out);
}

// Round 3
// 323.640 us; speedup vs baseline: 2.0852x; 2.0852x over previous
//
#include <hip/hip_runtime.h>
#include <cstdint>
#include <cstddef>

// Problem: B=32, C=768, H=W=32 (HW=1024).
// out[b,c,hw] = (0.5 + 0.5 * cos_gate(b,c)) * X[b,c,hw]
// cos_gate = dot(K_c,V_c)/((||K_c||+1e-12)(||V_c||+1e-12)),
// K = Wk @ Xn, V = Wv @ Xn, Xn = X * rsqrt(mean_c X^2 + 1e-6).
//
// r3: (1) gemm = r1's proven 8-phase 256x256 kernel with an XCD-colocating
// block-id decode (6 blocks sharing a B-slice -> same XCD, co-dispatched) so
// stage loads are L2 hits inside the vmcnt(6) lead; (2) sumsq+xnt fused
// (X read from HBM once); (3) final_kernel fattened to 8 (b,c)/block.

#define B_   32
#define C_   768
#define HW_  1024
#define CHW_ (C_ * HW_)          // 786432
#define EPS_NORM 1e-6f
#define EPS_COS  1e-12f

using f32x4  = __attribute__((ext_vector_type(4))) float;
using bf16x8 = __attribute__((ext_vector_type(8))) short;   // 8 bf16 = 4 VGPRs

__device__ inline unsigned short f2bf(float f) {
    union { float f; unsigned u; } v; v.f = f;
    unsigned u = v.u;
    u += 0x7fffu + ((u >> 16) & 1u);        // round-to-nearest-even
    return (unsigned short)(u >> 16);
}

// async global->LDS, 16 B per lane. LDS dst is wave-uniform base + lane*16.
__device__ __forceinline__ void load16_lds(const unsigned short* g, short* l) {
    __builtin_amdgcn_global_load_lds(
        (const __attribute__((address_space(1))) unsigned int*)g,
        (__attribute__((address_space(3))) unsigned int*)l,
        16, 0, 0);
}

__device__ __forceinline__ void stage_half(const unsigned short* g, short* l,
                                           size_t toff, int ldsoff, int rs) {
    load16_lds(g + toff,                     l + ldsoff);
    load16_lds(g + toff + (size_t)rs * 768,  l + ldsoff + 4096);
}

// ---------------------------------------------------------------------------
// K1: cast + row-interleave first 1536 rows of W_in (fp32) -> bf16.
// Wst[2c+s] = W[s*768 + c]. grid 1536 blocks x 192 threads (1 float4/thread).
// ---------------------------------------------------------------------------
__global__ void wconv_kernel(const float* __restrict__ W, unsigned short* __restrict__ Wst) {
    const int orow = blockIdx.x;               // 0..1535
    const int c4   = threadIdx.x;              // 0..191
    const int irow = (orow & 1) * 768 + (orow >> 1);
    const float4 v = reinterpret_cast<const float4*>(W + (size_t)irow * 768)[c4];
    ushort4 o;
    o.x = f2bf(v.x); o.y = f2bf(v.y); o.z = f2bf(v.z); o.w = f2bf(v.w);
    reinterpret_cast<ushort4*>(Wst + (size_t)orow * 768)[c4] = o;
}

// ---------------------------------------------------------------------------
// K2 (fused sumsq + normalize + transpose):
// pass 1: block (b, 64-hw slice) accumulates sum_c X^2 over all 768 c
//         (196 KB X slice, HBM); per-hw scale = rsqrt(ss/768+eps) in LDS.
// pass 2: re-read the slice (L2/L3-hot), scale, bf16, 64x64 LDS transpose,
//         write Xnt[b][hw][c]. grid (16 hw, 32 b), block 256.
// ---------------------------------------------------------------------------
__global__ __launch_bounds__(256) void norm_kernel(const float* __restrict__ X,
                                                   unsigned short* __restrict__ Xnt) {
    const int b   = blockIdx.y;
    const int hw0 = blockIdx.x * 64;
    const int tid = threadIdx.x;
    __shared__ float4 P[256];          // partials, then per-hw-quad scales in P[0..15]
    __shared__ short  T[64][78];       // transpose tile (pad 78: ~2-way, free)

    const int cg = tid >> 4;           // c group 0..15
    const int q4 = tid & 15;           // hw quad 0..15
    const float* xb = X + (size_t)b * CHW_ + hw0 + q4 * 4;
    float4 s = {0.f, 0.f, 0.f, 0.f};
    #pragma unroll 4
    for (int c = cg; c < 768; c += 16) {
        float4 v = *reinterpret_cast<const float4*>(xb + (size_t)c * HW_);
        s.x += v.x * v.x; s.y += v.y * v.y; s.z += v.z * v.z; s.w += v.w * v.w;
    }
    P[tid] = s;
    __syncthreads();
    if (tid < 16) {
        float4 a = P[tid];
        #pragma unroll
        for (int g = 1; g < 16; ++g) {
            float4 v = P[g * 16 + tid];
            a.x += v.x; a.y += v.y; a.z += v.z; a.w += v.w;
        }
        float4 sc;
        sc.x = rsqrtf(a.x * (1.f / 768.f) + EPS_NORM);
        sc.y = rsqrtf(a.y * (1.f / 768.f) + EPS_NORM);
        sc.z = rsqrtf(a.z * (1.f / 768.f) + EPS_NORM);
        sc.w = rsqrtf(a.w * (1.f / 768.f) + EPS_NORM);
        P[tid] = sc;
    }
    __syncthreads();

    #pragma unroll 1
    for (int ch = 0; ch < 12; ++ch) {
        const int c0 = ch * 64;
        #pragma unroll
        for (int it = 0; it < 4; ++it) {
            int q  = it * 256 + tid;    // 0..1023
            int r  = q >> 4;            // c row in tile
            int c4 = (q & 15) * 4;      // hw col in tile
            const float4 x = *reinterpret_cast<const float4*>(
                X + (size_t)b * CHW_ + (size_t)(c0 + r) * HW_ + hw0 + c4);
            const float4 sc = P[q & 15];
            ushort4 o;
            o.x = f2bf(x.x * sc.x); o.y = f2bf(x.y * sc.y);
            o.z = f2bf(x.z * sc.z); o.w = f2bf(x.w * sc.w);
            *reinterpret_cast<ushort4*>(&T[r][c4]) = o;
        }
        __syncthreads();
        #pragma unroll
        for (int it = 0; it < 2; ++it) {
            int q  = it * 256 + tid;    // 0..511
            int rp = q >> 3;            // hw row
            int cc = (q & 7) * 8;       // c chunk
            __align__(16) unsigned short tmp[8];
            #pragma unroll
            for (int j = 0; j < 8; ++j) tmp[j] = (unsigned short)T[cc + j][rp];
            *reinterpret_cast<uint4*>(
                Xnt + (size_t)b * CHW_ + (size_t)(hw0 + rp) * C_ + c0 + cc) =
                *reinterpret_cast<const uint4*>(tmp);
        }
        __syncthreads();
    }
}

// ---------------------------------------------------------------------------
// K4: 256x256 (BK=64) 8-phase GEMM + fused row reductions (r1 schedule,
// unchanged) with XCD-colocating block decode: the 6 c-tile blocks sharing a
// B-slice map to the same XCD (assuming xcd = hwid % 8) and adjacent w, so
// their B stage-loads hit that XCD's L2 inside the vmcnt(6) lead.
// ---------------------------------------------------------------------------
template<int P, bool VM>
__device__ __forceinline__ void phase(const short* Ar, const short* Br,
        const unsigned short* gs, short* ls, size_t toff, int ldsoff, int rs,
        int l15, int wgm64, int wnl64, int slot0, int slot1,
        bf16x8 (&bA)[2][2], bf16x8 (&bB)[4][2], f32x4 (&acc)[8][4]) {
    if constexpr (P == 0) {            // B-frags loaded once per K-tile
        #pragma unroll
        for (int ni = 0; ni < 4; ++ni) {
            const int rB = wnl64 + (ni << 4) + l15;
            bB[ni][0] = *reinterpret_cast<const bf16x8*>(Br + (rB << 6) + slot0);
            bB[ni][1] = *reinterpret_cast<const bf16x8*>(Br + (rB << 6) + slot1);
        }
    }
    #pragma unroll
    for (int s = 0; s < 2; ++s) {      // A-frags mi = 2P, 2P+1
        const int rA = ((((P & 1) << 1) | s) << 4) + l15 + wgm64;
        bA[s][0] = *reinterpret_cast<const bf16x8*>(Ar + (rA << 6) + slot0);
        bA[s][1] = *reinterpret_cast<const bf16x8*>(Ar + (rA << 6) + slot1);
    }
    stage_half(gs, ls, toff, ldsoff, rs);
    if (VM) asm volatile("s_waitcnt vmcnt(6)" ::: "memory");
    __builtin_amdgcn_sched_barrier(0);
    __builtin_amdgcn_s_barrier();
    asm volatile("s_waitcnt lgkmcnt(0)" ::: "memory");
    __builtin_amdgcn_sched_barrier(0);
    __builtin_amdgcn_s_setprio(1);
    #pragma unroll
    for (int s = 0; s < 2; ++s)
        #pragma unroll
        for (int ni = 0; ni < 4; ++ni) {
            acc[(P << 1) | s][ni] = __builtin_amdgcn_mfma_f32_16x16x32_bf16(
                bA[s][0], bB[ni][0], acc[(P << 1) | s][ni], 0, 0, 0);
            acc[(P << 1) | s][ni] = __builtin_amdgcn_mfma_f32_16x16x32_bf16(
                bA[s][1], bB[ni][1], acc[(P << 1) | s][ni], 0, 0, 0);
        }
    __builtin_amdgcn_s_setprio(0);
    __builtin_amdgcn_sched_barrier(0);
    __builtin_amdgcn_s_barrier();
    __builtin_amdgcn_sched_barrier(0);
}

__global__ __launch_bounds__(512, 2) void gemm_kernel(
        const unsigned short* __restrict__ Wst,   // [1536][768] bf16, interleaved K/V
        const unsigned short* __restrict__ Xnt,   // [B][HW][C] bf16
        float* __restrict__ wsA) {
    // XCD-colocate decode: h -> (slice, member). slice = (b, hw-tile), 128 of
    // them; member = c-tile 0..5. All 6 members share xcd = slice&7.
    const int h     = blockIdx.x;                 // 0..767
    const int xcd   = h & 7;
    const int w     = h >> 3;                     // 0..95
    const int slice = ((w / 6) << 3) + xcd;       // 0..127
    const int memb  = w % 6;
    const int n0    = (slice & 3) * 256;
    const int c0    = memb * 256;
    const int b     = slice >> 2;

    const int tid  = threadIdx.x;
    const int lane = tid & 63;
    const int wave = tid >> 6;
    const int l15  = lane & 15;
    const int quad = lane >> 4;
    const int wgm64 = (wave >> 2) << 6;           // A lr offset: 0 / 64
    const int wq    = wave & 3;
    const int wnl64 = (wq & 1) << 6;              // B lr offset within half
    const int hB    = wq >> 1;                    // wave's fixed B half

    const int lb7   = l15 & 7;
    const int slot0 = (quad ^ lb7) << 3;          // k-step 0 swizzled slot (shorts)
    const int slot1 = ((quad + 4) ^ lb7) << 3;    // k-step 1

    __shared__ __align__(16) short sA[2][2][128][64];
    __shared__ __align__(16) short sB[2][2][128][64];

    // staging map: r0 = local row 0..127, chunk pre-swizzled by (r0&7)
    const int r0      = tid >> 3;
    const size_t toff = (size_t)r0 * 768 + (((tid & 7) ^ (r0 & 7)) << 3);
    const int ldsoff  = (r0 & ~7) << 6;           // wave-uniform per 8-lane row group

    const unsigned short* Ab = Wst + (size_t)c0 * 768;
    const unsigned short* Bb = Xnt + (size_t)b * CHW_ + (size_t)n0 * 768;

    f32x4 acc[8][4];
    const f32x4 zero = {0.f, 0.f, 0.f, 0.f};
    #pragma unroll
    for (int i = 0; i < 8; ++i)
        #pragma unroll
        for (int j = 0; j < 4; ++j) acc[i][j] = zero;

    bf16x8 bA[2][2], bB[4][2];

    // prologue: tile0 fully + B(T1)h0/h1 + A(T1)h0  (A(T1)h1 comes in ph1)
    stage_half(Ab,                &sA[0][0][0][0], toff, ldsoff, 128);
    stage_half(Ab + 64 * 768,     &sA[0][1][0][0], toff, ldsoff, 128);
    stage_half(Bb,                &sB[0][0][0][0], toff, ldsoff, 64);
    stage_half(Bb + 128 * 768,    &sB[0][1][0][0], toff, ldsoff, 64);
    stage_half(Bb + 64,           &sB[1][0][0][0], toff, ldsoff, 64);
    stage_half(Bb + 128 * 768 + 64, &sB[1][1][0][0], toff, ldsoff, 64);
    stage_half(Ab + 64,           &sA[1][0][0][0], toff, ldsoff, 128);
    asm volatile("s_waitcnt vmcnt(6)" ::: "memory");   // tile0's 8 loads done
    __builtin_amdgcn_s_barrier();
    __builtin_amdgcn_sched_barrier(0);

    for (int it = 0; it < 6; ++it) {
        const int kT1 = it * 128 + 64;
        int kT2 = it * 128 + 128; if (kT2 >= 768) kT2 -= 768;   // wrap: dead stages
        int kT3 = it * 128 + 192; if (kT3 >= 768) kT3 -= 768;

        // tile T0 (buf0), phases 1-4
        phase<0, false>(&sA[0][0][0][0], &sB[0][hB][0][0],
                        Ab + 64 * 768 + kT1, &sA[1][1][0][0], toff, ldsoff, 128,
                        l15, wgm64, wnl64, slot0, slot1, bA, bB, acc);
        phase<1, false>(&sA[0][0][0][0], nullptr,
                        Bb + kT2,            &sB[0][0][0][0], toff, ldsoff, 64,
                        l15, wgm64, wnl64, slot0, slot1, bA, bB, acc);
        phase<2, false>(&sA[0][1][0][0], nullptr,
                        Bb + 128 * 768 + kT2, &sB[0][1][0][0], toff, ldsoff, 64,
                        l15, wgm64, wnl64, slot0, slot1, bA, bB, acc);
        phase<3, true >(&sA[0][1][0][0], nullptr,
                        Ab + kT2,            &sA[0][0][0][0], toff, ldsoff, 128,
                        l15, wgm64, wnl64, slot0, slot1, bA, bB, acc);
        // tile T1 (buf1), phases 5-8
        phase<0, false>(&sA[1][0][0][0], &sB[1][hB][0][0],
                        Ab + 64 * 768 + kT2, &sA[0][1][0][0], toff, ldsoff, 128,
                        l15, wgm64, wnl64, slot0, slot1, bA, bB, acc);
        phase<1, false>(&sA[1][0][0][0], nullptr,
                        Bb + kT3,            &sB[1][0][0][0], toff, ldsoff, 64,
                        l15, wgm64, wnl64, slot0, slot1, bA, bB, acc);
        phase<2, false>(&sA[1][1][0][0], nullptr,
                        Bb + 128 * 768 + kT3, &sB[1][1][0][0], toff, ldsoff, 64,
                        l15, wgm64, wnl64, slot0, slot1, bA, bB, acc);
        phase<3, true >(&sA[1][1][0][0], nullptr,
                        Ab + kT3,            &sA[1][0][0][0], toff, ldsoff, 128,
                        l15, wgm64, wnl64, slot0, slot1, bA, bB, acc);
    }
    asm volatile("s_waitcnt vmcnt(0)" ::: "memory");   // drain dead prefetches

    // epilogue: rows (4q..4q+3) of each acc quad are (K,V,K,V) of 2 channels.
    #pragma unroll
    for (int mi = 0; mi < 8; ++mi) {
        float d0 = 0.f, e0 = 0.f, f0 = 0.f, d1 = 0.f, e1 = 0.f, f1 = 0.f;
        #pragma unroll
        for (int ni = 0; ni < 4; ++ni) {
            f32x4 a = acc[mi][ni];
            d0 += a[0] * a[1]; e0 += a[0] * a[0]; f0 += a[1] * a[1];
            d1 += a[2] * a[3]; e1 += a[2] * a[2]; f1 += a[3] * a[3];
        }
        #pragma unroll
        for (int off = 1; off < 16; off <<= 1) {
            d0 += __shfl_xor(d0, off); e0 += __shfl_xor(e0, off); f0 += __shfl_xor(f0, off);
            d1 += __shfl_xor(d1, off); e1 += __shfl_xor(e1, off); f1 += __shfl_xor(f1, off);
        }
        if (l15 == 0) {
            const int ch = (c0 >> 1) + wgm64 + (mi << 3) + (quad << 1);
            float* dst = wsA + ((size_t)b * C_ + ch) * 3;
            atomicAdd(dst + 0, d0); atomicAdd(dst + 1, e0); atomicAdd(dst + 2, f0);
            atomicAdd(dst + 3, d1); atomicAdd(dst + 4, e1); atomicAdd(dst + 5, f1);
        }
    }
}

// ---------------------------------------------------------------------------
// K5: out = X * gate. 8 (b,c) rows per block (32 KB/block), gate per row.
// ---------------------------------------------------------------------------
__global__ __launch_bounds__(256) void final_kernel(const float* __restrict__ X,
                                                    const float* __restrict__ wsA,
                                                    float* __restrict__ out) {
    const int bc0 = blockIdx.x * 8;
    const int tid = threadIdx.x;
    #pragma unroll
    for (int j = 0; j < 8; ++j) {
        const int bc = bc0 + j;
        const float* a = wsA + (size_t)bc * 3;
        const float pd = a[0], pk = a[1], pv = a[2];
        const float g = 0.5f * (pd / ((sqrtf(pk) + EPS_COS) * (sqrtf(pv) + EPS_COS))) + 0.5f;
        const size_t i4 = (size_t)bc * 256 + tid;
        float4 x = reinterpret_cast<const float4*>(X)[i4];
        float4 o;
        o.x = x.x * g; o.y = x.y * g; o.z = x.z * g; o.w = x.w * g;
        reinterpret_cast<float4*>(out)[i4] = o;
    }
}

// ---------------------------------------------------------------------------
extern "C" void kernel_launch(void* const* d_in, const int* in_sizes, int n_in,
                              void* d_out, int out_size, void* d_ws, size_t ws_size,
                              hipStream_t stream) {
    const float* X = (const float*)d_in[0];   // [32,768,32,32]
    const float* W = (const float*)d_in[1];   // [2304,768]
    float* out = (float*)d_out;

    // workspace layout (bytes):
    //   [0,       294912)   wsA   float[32*768*3]  (dot, nk2, nv2)
    //   [425984,  2785280)  Wst   bf16[1536*768]   (interleaved K/V rows)
    //   [2785280, 53116928) Xnt   bf16[32][1024][768]
    char* ws = (char*)d_ws;
    float* wsA           = (float*)ws;
    unsigned short* Wst  = (unsigned short*)(ws + 425984);
    unsigned short* Xnt  = (unsigned short*)(ws + 2785280);

    hipMemsetAsync(ws, 0, 294912, stream);    // zero wsA

    wconv_kernel<<<dim3(1536),   192, 0, stream>>>(W, Wst);
    norm_kernel <<<dim3(16, 32), 256, 0, stream>>>(X, Xnt);
    gemm_kernel <<<dim3(768),    512, 0, stream>>>(Wst, Xnt, wsA);
    final_kernel<<<dim3(3072),   256, 0, stream>>>(X, wsA, out);
}